// Round 7
// baseline (201.089 us; speedup 1.0000x reference)
//
#include <hip/hip_runtime.h>
#include <hip/hip_bf16.h>
#include <stdint.h>

// y[p, j] = sum_i Alpha[p, i] * (X_ref[i] . X_in[j])^expK * [Z_ref[i] == Z[j]]
// Grouped formulation (4 element groups). Round-7 fused kernel: NO LDS, NO
// barriers — MFMA fragments loaded directly global->VGPR (Xr has zero
// intra-block reuse; cross-block reuse is L2's job via the XCD swizzle).
// Waves own disjoint 32 j-cols; per tile compute 128i in two 64-row halves.

typedef __attribute__((ext_vector_type(8))) short bf16x8;
typedef __attribute__((ext_vector_type(4))) float f32x4;
typedef __attribute__((ext_vector_type(4))) unsigned int u32x4;

#define DFEAT  384
#define NREF   8192
#define NIN    8192
#define NPROPS 64
#define BJ 128
#define BI 128
#define KSTEPS 6                   // K = 6 x (2 x 32)
#define CAP    8704                // 8192 + 4*128 (worst-case padded slots)
#define NSTRIP (CAP / BJ)          // 68

__device__ __forceinline__ unsigned short bfbits(float f) {
  __hip_bfloat16 h = __float2bfloat16(f);
  return __builtin_bit_cast(unsigned short, h);
}

__device__ __forceinline__ float pwr(float s, int expK) {
  if (expK == 2) return s * s;
  float r = 1.0f;
  for (int e = 0; e < expK; ++e) r *= s;
  return r;
}

// ---- stable partition of both label arrays (2 blocks, one each) ----
__global__ __launch_bounds__(256) void partition2_kernel(
    const int* __restrict__ Za, const int* __restrict__ Zb,
    int* __restrict__ perma, int* __restrict__ permb,
    int* __restrict__ goffa, int* __restrict__ goffb) {
  const int* Zin = blockIdx.x ? Zb : Za;
  int* perm = blockIdx.x ? permb : perma;
  int* goff = blockIdx.x ? goffb : goffa;

  __shared__ int cnt[256][4];
  __shared__ int gstart[4];
  __shared__ int gtot[4];
  const int t = threadIdx.x;
  const int base = t * 32;           // 8192 / 256

  int c[4] = {0, 0, 0, 0};
  int zloc[32];
  #pragma unroll
  for (int e = 0; e < 32; ++e) {
    zloc[e] = (Zin[base + e] - 1) & 3;   // labels are 1..4
    ++c[zloc[e]];
  }
  #pragma unroll
  for (int b = 0; b < 4; ++b) cnt[t][b] = c[b];
  __syncthreads();

  const int w = t >> 6, l = t & 63;
  {
    int v0 = cnt[4 * l + 0][w], v1 = cnt[4 * l + 1][w];
    int v2 = cnt[4 * l + 2][w], v3 = cnt[4 * l + 3][w];
    int s = v0 + v1 + v2 + v3;
    int inc = s;
    #pragma unroll
    for (int d = 1; d < 64; d <<= 1) {
      int o = __shfl_up(inc, d, 64);
      if (l >= d) inc += o;
    }
    const int excl = inc - s;
    cnt[4 * l + 0][w] = excl;
    cnt[4 * l + 1][w] = excl + v0;
    cnt[4 * l + 2][w] = excl + v0 + v1;
    cnt[4 * l + 3][w] = excl + v0 + v1 + v2;
    if (l == 63) gtot[w] = inc;
  }
  __syncthreads();

  if (t == 0) {
    int off = 0;
    #pragma unroll
    for (int b = 0; b < 4; ++b) {
      gstart[b] = off; goff[b] = off;
      off += ((gtot[b] + 127) >> 7) << 7;   // pad to 128
    }
    goff[4] = off;
  }
  __syncthreads();

  for (int s = t; s < CAP; s += 256) perm[s] = -1;
  __syncthreads();

  int pos[4];
  #pragma unroll
  for (int b = 0; b < 4; ++b) pos[b] = gstart[b] + cnt[t][b];
  #pragma unroll
  for (int e = 0; e < 32; ++e) {
    const int z = zloc[e];
    perm[pos[z]++] = base + e;
  }
}

// ---- merged gather: Xr (perm_i), Xi (perm_j), Alpha (perm_i, permuted) ----
#define XSEC (CAP * (DFEAT / 4) / 256)     // 3264 blocks per X section
__global__ void gather_all(const float* __restrict__ Xr_in,
                           const float* __restrict__ Xi_in,
                           const float* __restrict__ Al_in,
                           const int* __restrict__ perm_i,
                           const int* __restrict__ perm_j,
                           __hip_bfloat16* __restrict__ Xr_g,
                           __hip_bfloat16* __restrict__ Xi_g,
                           __hip_bfloat16* __restrict__ Ab_g) {
  const int b = blockIdx.x;
  if (b < 2 * XSEC) {
    const bool isA = (b < XSEC);
    const float* in = isA ? Xr_in : Xi_in;
    const int* perm = isA ? perm_i : perm_j;
    __hip_bfloat16* out = isA ? Xr_g : Xi_g;
    const int idx = (isA ? b : b - XSEC) * 256 + threadIdx.x;
    const int per_row = DFEAT / 4;
    const int slot = idx / per_row;
    const int c4 = (idx % per_row) * 4;
    const int src = perm[slot];
    ushort4 o = make_ushort4(0, 0, 0, 0);
    if (src >= 0) {
      float4 v = *reinterpret_cast<const float4*>(in + (size_t)src * DFEAT + c4);
      o.x = bfbits(v.x); o.y = bfbits(v.y); o.z = bfbits(v.z); o.w = bfbits(v.w);
    }
    *reinterpret_cast<ushort4*>(out + (size_t)slot * DFEAT + c4) = o;
  } else {
    // Ab_g[p][32b + l4*8 + eh*4 + r] = Alpha[p][perm_i[32b + eh*16 + l4*4 + r]]
    const int t = (b - 2 * XSEC) * 256 + threadIdx.x;   // NPROPS * CAP/4
    const int per_row = CAP / 4;
    const int p  = t / per_row;
    const int c4 = t % per_row;
    const int blk = c4 >> 3;
    const int g   = c4 & 7;
    const int l4g = g >> 1;
    const int eh  = g & 1;
    ushort4 o;
    unsigned short* op = &o.x;
    #pragma unroll
    for (int r = 0; r < 4; ++r) {
      const int slot = blk * 32 + eh * 16 + l4g * 4 + r;
      const int src = perm_i[slot];
      op[r] = (src >= 0) ? bfbits(Al_in[(size_t)p * NREF + src]) : (unsigned short)0;
    }
    *reinterpret_cast<ushort4*>(Ab_g + (size_t)p * CAP + blk * 32 + l4g * 8 + eh * 4) = o;
  }
}

// sum nsplit partials and scatter slot -> original column via perm_j
__global__ void reduce_scatter(const float* __restrict__ partial,
                               const int* __restrict__ permj,
                               float* __restrict__ out, int nsplit) {
  const int idx = blockIdx.x * blockDim.x + threadIdx.x;  // NPROPS * CAP
  const int p = idx / CAP;
  const int slot = idx % CAP;
  const int dst = permj[slot];
  if (dst < 0) return;
  float s = 0.f;
  for (int sp = 0; sp < nsplit; ++sp)
    s += partial[(size_t)sp * NPROPS * CAP + (size_t)p * CAP + slot];
  out[(size_t)p * NIN + dst] = s;
}

__global__ __launch_bounds__(256, 4) void fused_poly_kernel(
    const __hip_bfloat16* __restrict__ Xr,   // [CAP][DFEAT] gathered ref rows
    const __hip_bfloat16* __restrict__ Xi,   // [CAP][DFEAT] gathered query rows
    const __hip_bfloat16* __restrict__ Abp,  // [NPROPS][CAP] gathered+permuted
    const int* __restrict__ ioff,            // [5] padded i-group offsets
    const int* __restrict__ joff,            // [5] padded j-group offsets
    const int* __restrict__ expKp,
    float* __restrict__ partial,             // [nsplit][NPROPS][CAP]
    int nsplit, int chunk)                   // chunk = gridDim.x / 8
{
  // XCD-chunked bijective swizzle (kept: round-6 proved FETCH 45->17MB)
  const int flat = blockIdx.x;
  const int newflat = (flat & 7) * chunk + (flat >> 3);
  const int strip = newflat / nsplit;
  const int split = newflat % nsplit;
  const int j0 = strip * BJ;
  if (j0 >= joff[4]) return;                 // fully-pad strip

  int grp = 0;
  grp += (j0 >= joff[1]);
  grp += (j0 >= joff[2]);
  grp += (j0 >= joff[3]);
  const int ibase = ioff[grp];
  const int ntiles_g = (ioff[grp + 1] - ibase) / BI;
  const int tb = ntiles_g / nsplit;
  const int rem = ntiles_g % nsplit;
  const int ntiles = tb + (split < rem ? 1 : 0);
  const int tile_begin = split * tb + (split < rem ? split : rem);

  const int tid  = threadIdx.x;
  const int wid  = tid >> 6;
  const int lane = tid & 63;
  const int l15  = lane & 15;
  const int l4   = lane >> 4;
  const int jw   = j0 + wid * 32;            // this wave's 32 j-cols

  const int expK = *expKp;

  // B-fragment per-lane base (constant across tiles): row jw+n*16+l15
  const __hip_bfloat16* xiB = Xi + (size_t)(jw + l15) * DFEAT + l4 * 8;

  f32x4 accO[4][2];                          // p 64 x j 32 per wave
  #pragma unroll
  for (int a = 0; a < 4; ++a)
    #pragma unroll
    for (int n = 0; n < 2; ++n)
      accO[a][n] = (f32x4){0.f, 0.f, 0.f, 0.f};

  #pragma unroll 1
  for (int t = 0; t < ntiles; ++t) {
    const int i0 = ibase + (tile_begin + t) * BI;

    #pragma unroll 1
    for (int h = 0; h < 2; ++h) {            // 64-row i-halves
      const __hip_bfloat16* xrA =
          Xr + (size_t)(i0 + h * 64 + l15) * DFEAT + l4 * 8;

      f32x4 acc[4][2];                       // S half-tile 64i x 32j
      #pragma unroll
      for (int m = 0; m < 4; ++m)
        #pragma unroll
        for (int n = 0; n < 2; ++n)
          acc[m][n] = (f32x4){0.f, 0.f, 0.f, 0.f};

      // ---- QK^T over K=384, fully unrolled, direct global->VGPR ----
      #pragma unroll
      for (int kk = 0; kk < KSTEPS; ++kk) {
        #pragma unroll
        for (int kap = 0; kap < 2; ++kap) {
          const int co = kk * 64 + kap * 32;   // element column offset
          bf16x8 aF[4], bF[2];
          #pragma unroll
          for (int m = 0; m < 4; ++m)
            aF[m] = *reinterpret_cast<const bf16x8*>(xrA + m * (16 * DFEAT) + co);
          #pragma unroll
          for (int n = 0; n < 2; ++n)
            bF[n] = *reinterpret_cast<const bf16x8*>(xiB + n * (16 * DFEAT) + co);
          #pragma unroll
          for (int m = 0; m < 4; ++m)
            #pragma unroll
            for (int n = 0; n < 2; ++n)
              acc[m][n] = __builtin_amdgcn_mfma_f32_16x16x32_bf16(
                  aF[m], bF[n], acc[m][n], 0, 0, 0);
        }
      }

      // ---- Alpha fragments (hoisted; latency hides under pack VALU) ----
      bf16x8 aP[2][4];
      #pragma unroll
      for (int ks = 0; ks < 2; ++ks)
        #pragma unroll
        for (int a = 0; a < 4; ++a)
          aP[ks][a] = *reinterpret_cast<const bf16x8*>(
              Abp + (size_t)(a * 16 + l15) * CAP + i0 + h * 64 + ks * 32 + l4 * 8);

      // ---- square + pack to bf16 (groups pre-matched: no mask) ----
      uint32_t lov[4][2], hiv[4][2];
      #pragma unroll
      for (int m = 0; m < 4; ++m) {
        #pragma unroll
        for (int n = 0; n < 2; ++n) {
          const float p0 = pwr(acc[m][n][0], expK);
          const float p1 = pwr(acc[m][n][1], expK);
          const float p2 = pwr(acc[m][n][2], expK);
          const float p3 = pwr(acc[m][n][3], expK);
          lov[m][n] = (uint32_t)bfbits(p0) | ((uint32_t)bfbits(p1) << 16);
          hiv[m][n] = (uint32_t)bfbits(p2) | ((uint32_t)bfbits(p3) << 16);
        }
      }

      // ---- lane-local PV: accO[p][j] += Alpha[p, i-half] * P ----
      #pragma unroll
      for (int ks = 0; ks < 2; ++ks) {
        #pragma unroll
        for (int n = 0; n < 2; ++n) {
          u32x4 tw;
          tw[0] = lov[2 * ks][n];
          tw[1] = hiv[2 * ks][n];
          tw[2] = lov[2 * ks + 1][n];
          tw[3] = hiv[2 * ks + 1][n];
          const bf16x8 bP = __builtin_bit_cast(bf16x8, tw);
          #pragma unroll
          for (int a = 0; a < 4; ++a)
            accO[a][n] = __builtin_amdgcn_mfma_f32_16x16x32_bf16(
                aP[ks][a], bP, accO[a][n], 0, 0, 0);
        }
      }
    }
  }

  // ---- epilogue: each wave owns disjoint j-cols -> direct store ----
  float* po = partial + (size_t)split * NPROPS * CAP;
  #pragma unroll
  for (int a = 0; a < 4; ++a)
    #pragma unroll
    for (int n = 0; n < 2; ++n)
      #pragma unroll
      for (int r = 0; r < 4; ++r) {
        const int p = a * 16 + l4 * 4 + r;
        po[(size_t)p * CAP + jw + n * 16 + l15] = accO[a][n][r];
      }
}

extern "C" void kernel_launch(void* const* d_in, const int* in_sizes, int n_in,
                              void* d_out, int out_size, void* d_ws, size_t ws_size,
                              hipStream_t stream) {
  (void)in_sizes; (void)n_in; (void)out_size;
  const float* Alpha = (const float*)d_in[0];
  const float* X_ref = (const float*)d_in[1];
  const float* desc  = (const float*)d_in[2];
  const int*   Z_ref = (const int*)d_in[3];
  const int*   Z     = (const int*)d_in[4];
  const int*   expK  = (const int*)d_in[5];
  float* out = (float*)d_out;

  char* ws = (char*)d_ws;
  size_t off = 0;
  auto alloc = [&](size_t b) { void* p = ws + off; off = (off + b + 255) & ~255ULL; return p; };

  int* perm_i = (int*)alloc(CAP * 4);
  int* perm_j = (int*)alloc(CAP * 4);
  int* ioff   = (int*)alloc(8 * 4);
  int* joff   = (int*)alloc(8 * 4);
  __hip_bfloat16* Xr_g = (__hip_bfloat16*)alloc((size_t)CAP * DFEAT * 2);
  __hip_bfloat16* Xi_g = (__hip_bfloat16*)alloc((size_t)CAP * DFEAT * 2);
  __hip_bfloat16* Ab_g = (__hip_bfloat16*)alloc((size_t)NPROPS * CAP * 2);

  int nsplit = 8;
  while (nsplit > 1 && off + (size_t)nsplit * NPROPS * CAP * 4 > ws_size) nsplit >>= 1;
  float* partial = (float*)alloc((size_t)nsplit * NPROPS * CAP * 4);

  partition2_kernel<<<dim3(2), 256, 0, stream>>>(
      Z_ref, Z, perm_i, perm_j, ioff, joff);

  gather_all<<<dim3(2 * XSEC + NPROPS * (CAP / 4) / 256), 256, 0, stream>>>(
      X_ref, desc, Alpha, perm_i, perm_j, Xr_g, Xi_g, Ab_g);

  const int grid = NSTRIP * nsplit;          // 544 at nsplit=8 (multiple of 8)
  fused_poly_kernel<<<dim3(grid), 256, 0, stream>>>(
      Xr_g, Xi_g, Ab_g, ioff, joff, expK, partial, nsplit, grid / 8);

  reduce_scatter<<<dim3(NPROPS * CAP / 256), 256, 0, stream>>>(
      partial, perm_j, out, nsplit);
}

// Round 8
// 152.132 us; speedup vs baseline: 1.3218x; 1.3218x over previous
//
#include <hip/hip_runtime.h>
#include <hip/hip_bf16.h>
#include <stdint.h>

// y[p, j] = sum_i Alpha[p, i] * (X_ref[i] . X_in[j])^expK * [Z_ref[i] == Z[j]]
// Grouped formulation (4 element groups). Round-8 fused kernel: NO LDS, NO
// barriers; B (Xi) fragments held in registers for the whole kernel (96 VGPR,
// loaded once); A streams global->VGPR (L1/L2-hot via XCD swizzle).
// launch_bounds(256,2) -> 256-VGPR cap (round-7's spill regression fixed).

typedef __attribute__((ext_vector_type(8))) short bf16x8;
typedef __attribute__((ext_vector_type(4))) float f32x4;
typedef __attribute__((ext_vector_type(4))) unsigned int u32x4;

#define DFEAT  384
#define NREF   8192
#define NIN    8192
#define NPROPS 64
#define BJ 128
#define BI 128
#define KSTEPS 6                   // K = 6 x (2 x 32)
#define CAP    8704                // 8192 + 4*128 (worst-case padded slots)
#define NSTRIP (CAP / BJ)          // 68

__device__ __forceinline__ unsigned short bfbits(float f) {
  __hip_bfloat16 h = __float2bfloat16(f);
  return __builtin_bit_cast(unsigned short, h);
}

__device__ __forceinline__ float pwr(float s, int expK) {
  if (expK == 2) return s * s;
  float r = 1.0f;
  for (int e = 0; e < expK; ++e) r *= s;
  return r;
}

// ---- stable partition of both label arrays (2 blocks, one each) ----
__global__ __launch_bounds__(256) void partition2_kernel(
    const int* __restrict__ Za, const int* __restrict__ Zb,
    int* __restrict__ perma, int* __restrict__ permb,
    int* __restrict__ goffa, int* __restrict__ goffb) {
  const int* Zin = blockIdx.x ? Zb : Za;
  int* perm = blockIdx.x ? permb : perma;
  int* goff = blockIdx.x ? goffb : goffa;

  __shared__ int cnt[256][4];
  __shared__ int gstart[4];
  __shared__ int gtot[4];
  const int t = threadIdx.x;
  const int base = t * 32;           // 8192 / 256

  int c[4] = {0, 0, 0, 0};
  int zloc[32];
  #pragma unroll
  for (int e = 0; e < 32; ++e) {
    zloc[e] = (Zin[base + e] - 1) & 3;   // labels are 1..4
    ++c[zloc[e]];
  }
  #pragma unroll
  for (int b = 0; b < 4; ++b) cnt[t][b] = c[b];
  __syncthreads();

  const int w = t >> 6, l = t & 63;
  {
    int v0 = cnt[4 * l + 0][w], v1 = cnt[4 * l + 1][w];
    int v2 = cnt[4 * l + 2][w], v3 = cnt[4 * l + 3][w];
    int s = v0 + v1 + v2 + v3;
    int inc = s;
    #pragma unroll
    for (int d = 1; d < 64; d <<= 1) {
      int o = __shfl_up(inc, d, 64);
      if (l >= d) inc += o;
    }
    const int excl = inc - s;
    cnt[4 * l + 0][w] = excl;
    cnt[4 * l + 1][w] = excl + v0;
    cnt[4 * l + 2][w] = excl + v0 + v1;
    cnt[4 * l + 3][w] = excl + v0 + v1 + v2;
    if (l == 63) gtot[w] = inc;
  }
  __syncthreads();

  if (t == 0) {
    int off = 0;
    #pragma unroll
    for (int b = 0; b < 4; ++b) {
      gstart[b] = off; goff[b] = off;
      off += ((gtot[b] + 127) >> 7) << 7;   // pad to 128
    }
    goff[4] = off;
  }
  __syncthreads();

  for (int s = t; s < CAP; s += 256) perm[s] = -1;
  __syncthreads();

  int pos[4];
  #pragma unroll
  for (int b = 0; b < 4; ++b) pos[b] = gstart[b] + cnt[t][b];
  #pragma unroll
  for (int e = 0; e < 32; ++e) {
    const int z = zloc[e];
    perm[pos[z]++] = base + e;
  }
}

// ---- merged gather: Xr (perm_i), Xi (perm_j), Alpha (perm_i, permuted) ----
#define XSEC (CAP * (DFEAT / 4) / 256)     // 3264 blocks per X section
__global__ void gather_all(const float* __restrict__ Xr_in,
                           const float* __restrict__ Xi_in,
                           const float* __restrict__ Al_in,
                           const int* __restrict__ perm_i,
                           const int* __restrict__ perm_j,
                           __hip_bfloat16* __restrict__ Xr_g,
                           __hip_bfloat16* __restrict__ Xi_g,
                           __hip_bfloat16* __restrict__ Ab_g) {
  const int b = blockIdx.x;
  if (b < 2 * XSEC) {
    const bool isA = (b < XSEC);
    const float* in = isA ? Xr_in : Xi_in;
    const int* perm = isA ? perm_i : perm_j;
    __hip_bfloat16* out = isA ? Xr_g : Xi_g;
    const int idx = (isA ? b : b - XSEC) * 256 + threadIdx.x;
    const int per_row = DFEAT / 4;
    const int slot = idx / per_row;
    const int c4 = (idx % per_row) * 4;
    const int src = perm[slot];
    ushort4 o = make_ushort4(0, 0, 0, 0);
    if (src >= 0) {
      float4 v = *reinterpret_cast<const float4*>(in + (size_t)src * DFEAT + c4);
      o.x = bfbits(v.x); o.y = bfbits(v.y); o.z = bfbits(v.z); o.w = bfbits(v.w);
    }
    *reinterpret_cast<ushort4*>(out + (size_t)slot * DFEAT + c4) = o;
  } else {
    // Ab_g[p][32b + l4*8 + eh*4 + r] = Alpha[p][perm_i[32b + eh*16 + l4*4 + r]]
    const int t = (b - 2 * XSEC) * 256 + threadIdx.x;   // NPROPS * CAP/4
    const int per_row = CAP / 4;
    const int p  = t / per_row;
    const int c4 = t % per_row;
    const int blk = c4 >> 3;
    const int g   = c4 & 7;
    const int l4g = g >> 1;
    const int eh  = g & 1;
    ushort4 o;
    unsigned short* op = &o.x;
    #pragma unroll
    for (int r = 0; r < 4; ++r) {
      const int slot = blk * 32 + eh * 16 + l4g * 4 + r;
      const int src = perm_i[slot];
      op[r] = (src >= 0) ? bfbits(Al_in[(size_t)p * NREF + src]) : (unsigned short)0;
    }
    *reinterpret_cast<ushort4*>(Ab_g + (size_t)p * CAP + blk * 32 + l4g * 8 + eh * 4) = o;
  }
}

// sum nsplit partials and scatter slot -> original column via perm_j
__global__ void reduce_scatter(const float* __restrict__ partial,
                               const int* __restrict__ permj,
                               float* __restrict__ out, int nsplit) {
  const int idx = blockIdx.x * blockDim.x + threadIdx.x;  // NPROPS * CAP
  const int p = idx / CAP;
  const int slot = idx % CAP;
  const int dst = permj[slot];
  if (dst < 0) return;
  float s = 0.f;
  for (int sp = 0; sp < nsplit; ++sp)
    s += partial[(size_t)sp * NPROPS * CAP + (size_t)p * CAP + slot];
  out[(size_t)p * NIN + dst] = s;
}

__global__ __launch_bounds__(256, 2) void fused_poly_kernel(
    const __hip_bfloat16* __restrict__ Xr,   // [CAP][DFEAT] gathered ref rows
    const __hip_bfloat16* __restrict__ Xi,   // [CAP][DFEAT] gathered query rows
    const __hip_bfloat16* __restrict__ Abp,  // [NPROPS][CAP] gathered+permuted
    const int* __restrict__ ioff,            // [5] padded i-group offsets
    const int* __restrict__ joff,            // [5] padded j-group offsets
    const int* __restrict__ expKp,
    float* __restrict__ partial,             // [nsplit][NPROPS][CAP]
    int nsplit, int chunk)                   // chunk = gridDim.x / 8
{
  // XCD-chunked bijective swizzle (round-6 proved FETCH 45->17MB)
  const int flat = blockIdx.x;
  const int newflat = (flat & 7) * chunk + (flat >> 3);
  const int strip = newflat / nsplit;
  const int split = newflat % nsplit;
  const int j0 = strip * BJ;
  if (j0 >= joff[4]) return;                 // fully-pad strip

  int grp = 0;
  grp += (j0 >= joff[1]);
  grp += (j0 >= joff[2]);
  grp += (j0 >= joff[3]);
  const int ibase = ioff[grp];
  const int ntiles_g = (ioff[grp + 1] - ibase) / BI;
  const int tb = ntiles_g / nsplit;
  const int rem = ntiles_g % nsplit;
  const int ntiles = tb + (split < rem ? 1 : 0);
  const int tile_begin = split * tb + (split < rem ? split : rem);

  const int tid  = threadIdx.x;
  const int wid  = tid >> 6;
  const int lane = tid & 63;
  const int l15  = lane & 15;
  const int l4   = lane >> 4;
  const int jw   = j0 + wid * 32;            // this wave's 32 j-cols

  const int expK = *expKp;

  // ---- B (Xi) fragments for this wave's 32 j-cols, whole K: held in regs ----
  // 2 n-tiles x 12 k-slots x 16B = 96 VGPR, loaded ONCE per kernel.
  const __hip_bfloat16* xiB = Xi + (size_t)(jw + l15) * DFEAT + l4 * 8;
  bf16x8 bReg[2][12];
  #pragma unroll
  for (int n = 0; n < 2; ++n)
    #pragma unroll
    for (int ks = 0; ks < 12; ++ks)
      bReg[n][ks] = *reinterpret_cast<const bf16x8*>(
          xiB + n * (16 * DFEAT) + ks * 32);

  f32x4 accO[4][2];                          // p 64 x j 32 per wave
  #pragma unroll
  for (int a = 0; a < 4; ++a)
    #pragma unroll
    for (int n = 0; n < 2; ++n)
      accO[a][n] = (f32x4){0.f, 0.f, 0.f, 0.f};

  #pragma unroll 1
  for (int t = 0; t < ntiles; ++t) {
    const int i0 = ibase + (tile_begin + t) * BI;

    #pragma unroll 1
    for (int h = 0; h < 2; ++h) {            // 64-row i-halves
      const __hip_bfloat16* xrA =
          Xr + (size_t)(i0 + h * 64 + l15) * DFEAT + l4 * 8;

      f32x4 acc[4][2];                       // S half-tile 64i x 32j
      #pragma unroll
      for (int m = 0; m < 4; ++m)
        #pragma unroll
        for (int n = 0; n < 2; ++n)
          acc[m][n] = (f32x4){0.f, 0.f, 0.f, 0.f};

      // ---- QK^T over K=384: A streams global->VGPR, B from registers ----
      #pragma unroll
      for (int ks = 0; ks < 12; ++ks) {
        const int co = ks * 32;              // element column offset
        bf16x8 aF[4];
        #pragma unroll
        for (int m = 0; m < 4; ++m)
          aF[m] = *reinterpret_cast<const bf16x8*>(xrA + m * (16 * DFEAT) + co);
        #pragma unroll
        for (int m = 0; m < 4; ++m)
          #pragma unroll
          for (int n = 0; n < 2; ++n)
            acc[m][n] = __builtin_amdgcn_mfma_f32_16x16x32_bf16(
                aF[m], bReg[n][ks], acc[m][n], 0, 0, 0);
      }

      // ---- square + pack + lane-local PV (Alpha loaded inline) ----
      #pragma unroll
      for (int ks = 0; ks < 2; ++ks) {
        bf16x8 aP[4];
        #pragma unroll
        for (int a = 0; a < 4; ++a)
          aP[a] = *reinterpret_cast<const bf16x8*>(
              Abp + (size_t)(a * 16 + l15) * CAP + i0 + h * 64 + ks * 32 + l4 * 8);
        #pragma unroll
        for (int n = 0; n < 2; ++n) {
          const f32x4 s0 = acc[2 * ks][n];
          const f32x4 s1 = acc[2 * ks + 1][n];
          u32x4 tw;
          tw[0] = (uint32_t)bfbits(pwr(s0[0], expK)) |
                  ((uint32_t)bfbits(pwr(s0[1], expK)) << 16);
          tw[1] = (uint32_t)bfbits(pwr(s0[2], expK)) |
                  ((uint32_t)bfbits(pwr(s0[3], expK)) << 16);
          tw[2] = (uint32_t)bfbits(pwr(s1[0], expK)) |
                  ((uint32_t)bfbits(pwr(s1[1], expK)) << 16);
          tw[3] = (uint32_t)bfbits(pwr(s1[2], expK)) |
                  ((uint32_t)bfbits(pwr(s1[3], expK)) << 16);
          const bf16x8 bP = __builtin_bit_cast(bf16x8, tw);
          __builtin_amdgcn_s_setprio(1);
          #pragma unroll
          for (int a = 0; a < 4; ++a)
            accO[a][n] = __builtin_amdgcn_mfma_f32_16x16x32_bf16(
                aP[a], bP, accO[a][n], 0, 0, 0);
          __builtin_amdgcn_s_setprio(0);
        }
      }
    }
  }

  // ---- epilogue: each wave owns disjoint j-cols -> direct store ----
  float* po = partial + (size_t)split * NPROPS * CAP;
  #pragma unroll
  for (int a = 0; a < 4; ++a)
    #pragma unroll
    for (int n = 0; n < 2; ++n)
      #pragma unroll
      for (int r = 0; r < 4; ++r) {
        const int p = a * 16 + l4 * 4 + r;
        po[(size_t)p * CAP + jw + n * 16 + l15] = accO[a][n][r];
      }
}

extern "C" void kernel_launch(void* const* d_in, const int* in_sizes, int n_in,
                              void* d_out, int out_size, void* d_ws, size_t ws_size,
                              hipStream_t stream) {
  (void)in_sizes; (void)n_in; (void)out_size;
  const float* Alpha = (const float*)d_in[0];
  const float* X_ref = (const float*)d_in[1];
  const float* desc  = (const float*)d_in[2];
  const int*   Z_ref = (const int*)d_in[3];
  const int*   Z     = (const int*)d_in[4];
  const int*   expK  = (const int*)d_in[5];
  float* out = (float*)d_out;

  char* ws = (char*)d_ws;
  size_t off = 0;
  auto alloc = [&](size_t b) { void* p = ws + off; off = (off + b + 255) & ~255ULL; return p; };

  int* perm_i = (int*)alloc(CAP * 4);
  int* perm_j = (int*)alloc(CAP * 4);
  int* ioff   = (int*)alloc(8 * 4);
  int* joff   = (int*)alloc(8 * 4);
  __hip_bfloat16* Xr_g = (__hip_bfloat16*)alloc((size_t)CAP * DFEAT * 2);
  __hip_bfloat16* Xi_g = (__hip_bfloat16*)alloc((size_t)CAP * DFEAT * 2);
  __hip_bfloat16* Ab_g = (__hip_bfloat16*)alloc((size_t)NPROPS * CAP * 2);

  int nsplit = 8;
  while (nsplit > 1 && off + (size_t)nsplit * NPROPS * CAP * 4 > ws_size) nsplit >>= 1;
  float* partial = (float*)alloc((size_t)nsplit * NPROPS * CAP * 4);

  partition2_kernel<<<dim3(2), 256, 0, stream>>>(
      Z_ref, Z, perm_i, perm_j, ioff, joff);

  gather_all<<<dim3(2 * XSEC + NPROPS * (CAP / 4) / 256), 256, 0, stream>>>(
      X_ref, desc, Alpha, perm_i, perm_j, Xr_g, Xi_g, Ab_g);

  const int grid = NSTRIP * nsplit;          // 544 at nsplit=8 (multiple of 8)
  fused_poly_kernel<<<dim3(grid), 256, 0, stream>>>(
      Xr_g, Xi_g, Ab_g, ioff, joff, expK, partial, nsplit, grid / 8);

  reduce_scatter<<<dim3(NPROPS * CAP / 256), 256, 0, stream>>>(
      partial, perm_j, out, nsplit);
}

// Round 10
// 76.729 us; speedup vs baseline: 2.6207x; 1.9827x over previous
//
#include <hip/hip_runtime.h>
#include <hip/hip_bf16.h>
#include <stdint.h>

// y[p, j] = sum_i Alpha[p, i] * (X_ref[i] . X_in[j])^expK * [Z_ref[i] == Z[j]]
// Grouped formulation (4 element groups). Round-10: 512-thread / 8-wave block,
// per-wave 64x32 tiles (acc+accO = 64 VGPR) -> fits 128-VGPR cap at
// 2 blocks/CU = 16 waves/CU. BK=32 dbuf LDS (32KB), one barrier per K-step
// (r5-proven), lane-local PV (r4-proven), XCD-chunked swizzle (r6-proven).
// r9's NaN: staging offset used c*1024 ELEMENTS for 1KB chunks -> c*512 fixed.

typedef __attribute__((ext_vector_type(8))) short bf16x8;
typedef __attribute__((ext_vector_type(4))) float f32x4;
typedef __attribute__((ext_vector_type(4))) unsigned int u32x4;

#define DFEAT  384
#define NREF   8192
#define NIN    8192
#define NPROPS 64
#define BJ 128
#define BI 128
#define BK 32
#define KSTEPS (DFEAT / BK)        // 12
#define CAP    8704                // 8192 + 4*128 (worst-case padded slots)
#define NSTRIP (CAP / BJ)          // 68

__device__ __forceinline__ void gload_lds16(const void* g, void* l) {
  __builtin_amdgcn_global_load_lds(
      (const __attribute__((address_space(1))) void*)g,
      (__attribute__((address_space(3))) void*)l,
      16, 0, 0);
}

__device__ __forceinline__ unsigned short bfbits(float f) {
  __hip_bfloat16 h = __float2bfloat16(f);
  return __builtin_bit_cast(unsigned short, h);
}

__device__ __forceinline__ float pwr(float s, int expK) {
  if (expK == 2) return s * s;
  float r = 1.0f;
  for (int e = 0; e < expK; ++e) r *= s;
  return r;
}

// ---- stable partition of both label arrays (2 blocks, one each) ----
__global__ __launch_bounds__(256) void partition2_kernel(
    const int* __restrict__ Za, const int* __restrict__ Zb,
    int* __restrict__ perma, int* __restrict__ permb,
    int* __restrict__ goffa, int* __restrict__ goffb) {
  const int* Zin = blockIdx.x ? Zb : Za;
  int* perm = blockIdx.x ? permb : perma;
  int* goff = blockIdx.x ? goffb : goffa;

  __shared__ int cnt[256][4];
  __shared__ int gstart[4];
  __shared__ int gtot[4];
  const int t = threadIdx.x;
  const int base = t * 32;           // 8192 / 256

  int c[4] = {0, 0, 0, 0};
  int zloc[32];
  #pragma unroll
  for (int e = 0; e < 32; ++e) {
    zloc[e] = (Zin[base + e] - 1) & 3;   // labels are 1..4
    ++c[zloc[e]];
  }
  #pragma unroll
  for (int b = 0; b < 4; ++b) cnt[t][b] = c[b];
  __syncthreads();

  const int w = t >> 6, l = t & 63;
  {
    int v0 = cnt[4 * l + 0][w], v1 = cnt[4 * l + 1][w];
    int v2 = cnt[4 * l + 2][w], v3 = cnt[4 * l + 3][w];
    int s = v0 + v1 + v2 + v3;
    int inc = s;
    #pragma unroll
    for (int d = 1; d < 64; d <<= 1) {
      int o = __shfl_up(inc, d, 64);
      if (l >= d) inc += o;
    }
    const int excl = inc - s;
    cnt[4 * l + 0][w] = excl;
    cnt[4 * l + 1][w] = excl + v0;
    cnt[4 * l + 2][w] = excl + v0 + v1;
    cnt[4 * l + 3][w] = excl + v0 + v1 + v2;
    if (l == 63) gtot[w] = inc;
  }
  __syncthreads();

  if (t == 0) {
    int off = 0;
    #pragma unroll
    for (int b = 0; b < 4; ++b) {
      gstart[b] = off; goff[b] = off;
      off += ((gtot[b] + 127) >> 7) << 7;   // pad to 128
    }
    goff[4] = off;
  }
  __syncthreads();

  for (int s = t; s < CAP; s += 256) perm[s] = -1;
  __syncthreads();

  int pos[4];
  #pragma unroll
  for (int b = 0; b < 4; ++b) pos[b] = gstart[b] + cnt[t][b];
  #pragma unroll
  for (int e = 0; e < 32; ++e) {
    const int z = zloc[e];
    perm[pos[z]++] = base + e;
  }
}

// ---- merged gather: Xr (perm_i), Xi (perm_j), Alpha (perm_i, permuted) ----
#define XSEC (CAP * (DFEAT / 4) / 256)     // 3264 blocks per X section
__global__ void gather_all(const float* __restrict__ Xr_in,
                           const float* __restrict__ Xi_in,
                           const float* __restrict__ Al_in,
                           const int* __restrict__ perm_i,
                           const int* __restrict__ perm_j,
                           __hip_bfloat16* __restrict__ Xr_g,
                           __hip_bfloat16* __restrict__ Xi_g,
                           __hip_bfloat16* __restrict__ Ab_g) {
  const int b = blockIdx.x;
  if (b < 2 * XSEC) {
    const bool isA = (b < XSEC);
    const float* in = isA ? Xr_in : Xi_in;
    const int* perm = isA ? perm_i : perm_j;
    __hip_bfloat16* out = isA ? Xr_g : Xi_g;
    const int idx = (isA ? b : b - XSEC) * 256 + threadIdx.x;
    const int per_row = DFEAT / 4;
    const int slot = idx / per_row;
    const int c4 = (idx % per_row) * 4;
    const int src = perm[slot];
    ushort4 o = make_ushort4(0, 0, 0, 0);
    if (src >= 0) {
      float4 v = *reinterpret_cast<const float4*>(in + (size_t)src * DFEAT + c4);
      o.x = bfbits(v.x); o.y = bfbits(v.y); o.z = bfbits(v.z); o.w = bfbits(v.w);
    }
    *reinterpret_cast<ushort4*>(out + (size_t)slot * DFEAT + c4) = o;
  } else {
    // Ab_g[p][32b + l4*8 + eh*4 + r] = Alpha[p][perm_i[32b + eh*16 + l4*4 + r]]
    const int t = (b - 2 * XSEC) * 256 + threadIdx.x;   // NPROPS * CAP/4
    const int per_row = CAP / 4;
    const int p  = t / per_row;
    const int c4 = t % per_row;
    const int blk = c4 >> 3;
    const int g   = c4 & 7;
    const int l4g = g >> 1;
    const int eh  = g & 1;
    ushort4 o;
    unsigned short* op = &o.x;
    #pragma unroll
    for (int r = 0; r < 4; ++r) {
      const int slot = blk * 32 + eh * 16 + l4g * 4 + r;
      const int src = perm_i[slot];
      op[r] = (src >= 0) ? bfbits(Al_in[(size_t)p * NREF + src]) : (unsigned short)0;
    }
    *reinterpret_cast<ushort4*>(Ab_g + (size_t)p * CAP + blk * 32 + l4g * 8 + eh * 4) = o;
  }
}

// sum nsplit partials (vectorized x4) and scatter slot -> original column
__global__ void reduce_scatter(const float* __restrict__ partial,
                               const int* __restrict__ permj,
                               float* __restrict__ out, int nsplit) {
  const int idx = blockIdx.x * blockDim.x + threadIdx.x;  // NPROPS * CAP / 4
  const int per_row = CAP / 4;
  const int p = idx / per_row;
  const int s4 = (idx % per_row) * 4;
  float4 s = make_float4(0.f, 0.f, 0.f, 0.f);
  for (int sp = 0; sp < nsplit; ++sp) {
    float4 v = *reinterpret_cast<const float4*>(
        partial + (size_t)sp * NPROPS * CAP + (size_t)p * CAP + s4);
    s.x += v.x; s.y += v.y; s.z += v.z; s.w += v.w;
  }
  const int4 dst = *reinterpret_cast<const int4*>(permj + s4);
  float* po = out + (size_t)p * NIN;
  if (dst.x >= 0) po[dst.x] = s.x;
  if (dst.y >= 0) po[dst.y] = s.y;
  if (dst.z >= 0) po[dst.z] = s.z;
  if (dst.w >= 0) po[dst.w] = s.w;
}

__global__ __launch_bounds__(512, 4) void fused_poly_kernel(
    const __hip_bfloat16* __restrict__ Xr,   // [CAP][DFEAT] gathered ref rows
    const __hip_bfloat16* __restrict__ Xi,   // [CAP][DFEAT] gathered query rows
    const __hip_bfloat16* __restrict__ Abp,  // [NPROPS][CAP] gathered+permuted
    const int* __restrict__ ioff,            // [5] padded i-group offsets
    const int* __restrict__ joff,            // [5] padded j-group offsets
    const int* __restrict__ expKp,
    float* __restrict__ partial,             // [nsplit][NPROPS][CAP]
    int nsplit, int chunk)                   // chunk = gridDim.x / 8
{
  // XCD-chunked bijective swizzle (round-6 proved FETCH 45->17MB)
  const int flat = blockIdx.x;
  const int newflat = (flat & 7) * chunk + (flat >> 3);
  const int strip = newflat / nsplit;
  const int split = newflat % nsplit;
  const int j0 = strip * BJ;
  if (j0 >= joff[4]) return;                 // dead strip: never read downstream

  int grp = 0;
  grp += (j0 >= joff[1]);
  grp += (j0 >= joff[2]);
  grp += (j0 >= joff[3]);
  const int ibase = ioff[grp];
  const int ntiles_g = (ioff[grp + 1] - ibase) / BI;
  const int tb = ntiles_g / nsplit;
  const int rem = ntiles_g % nsplit;
  const int ntiles = tb + (split < rem ? 1 : 0);
  const int tile_begin = split * tb + (split < rem ? split : rem);

  const int tid  = threadIdx.x;
  const int wid  = tid >> 6;      // 8 waves
  const int lane = tid & 63;
  const int l15  = lane & 15;
  const int l4   = lane >> 4;
  const int wi   = wid >> 2;      // wave row over i (2)
  const int wj   = wid & 3;       // wave col over j (4)

  // LDS 32KB: lA dbuf 2x8KB, lB dbuf 2x8KB -> 2 blocks/CU (16 waves)
  __shared__ char smem[32768];
  __hip_bfloat16* lA = (__hip_bfloat16*)smem;            // [2][128*32]
  __hip_bfloat16* lB = (__hip_bfloat16*)(smem + 16384);  // [2][128*32]

  const int expK = *expKp;

  // staging: [128 rows][32 cols] bf16, row = 64B = 4 slots of 16B,
  // slot XOR-swizzled by row&3 (linear LDS dest, pre-swizzled source col).
  // chunk = wid: 16 rows x 32 cols = 1KB = 512 elements per array per wave.
  const int srow = lane >> 2;                       // row within 16-row chunk
  const int scol = ((lane & 3) ^ (srow & 3)) * 8;   // swizzled bf16 column

  auto stage = [&](int buf, int i0s, int kks) {
    const int grow = wid * 16 + srow;
    const size_t gc = (size_t)kks * BK + scol;
    gload_lds16(Xr + (size_t)(i0s + grow) * DFEAT + gc, lA + buf * 4096 + wid * 512);
    gload_lds16(Xi + (size_t)(j0  + grow) * DFEAT + gc, lB + buf * 4096 + wid * 512);
  };

  f32x4 accO[4][2];                       // p 64 x (this wave's j 32)
  #pragma unroll
  for (int a = 0; a < 4; ++a)
    #pragma unroll
    for (int n = 0; n < 2; ++n)
      accO[a][n] = (f32x4){0.f, 0.f, 0.f, 0.f};

  if (ntiles > 0) {
    int cur = 0;
    stage(0, ibase + tile_begin * BI, 0);
    asm volatile("s_waitcnt vmcnt(0)" ::: "memory");
    __builtin_amdgcn_s_barrier();

    for (int t = 0; t < ntiles; ++t) {
      const int i0 = ibase + (tile_begin + t) * BI;

      f32x4 acc[4][2];                    // S 64i x 32j per wave
      #pragma unroll
      for (int m = 0; m < 4; ++m)
        #pragma unroll
        for (int n = 0; n < 2; ++n)
          acc[m][n] = (f32x4){0.f, 0.f, 0.f, 0.f};

      // ---- QK^T: 12 K-steps, dbuf, ONE barrier per step (r5-proven) ----
      for (int kk = 0; kk < KSTEPS; ++kk) {
        if (kk < KSTEPS - 1) {
          stage(cur ^ 1, i0, kk + 1);
        } else if (t < ntiles - 1) {
          stage(cur ^ 1, i0 + BI, 0);
        }

        __builtin_amdgcn_s_setprio(1);
        {
          bf16x8 aF[4], bF[2];
          #pragma unroll
          for (int m = 0; m < 4; ++m) {
            const int rA = wi * 64 + m * 16 + l15;
            aF[m] = *reinterpret_cast<const bf16x8*>(
                (char*)(lA + cur * 4096) + rA * 64 + ((l4 ^ (rA & 3)) << 4));
          }
          #pragma unroll
          for (int n = 0; n < 2; ++n) {
            const int rB = wj * 32 + n * 16 + l15;
            bF[n] = *reinterpret_cast<const bf16x8*>(
                (char*)(lB + cur * 4096) + rB * 64 + ((l4 ^ (rB & 3)) << 4));
          }
          #pragma unroll
          for (int m = 0; m < 4; ++m)
            #pragma unroll
            for (int n = 0; n < 2; ++n)
              acc[m][n] = __builtin_amdgcn_mfma_f32_16x16x32_bf16(
                  aF[m], bF[n], acc[m][n], 0, 0, 0);
        }
        __builtin_amdgcn_s_setprio(0);
        // next-stage loads drained (hidden under compute) + my reads done
        asm volatile("s_waitcnt vmcnt(0) lgkmcnt(0)" ::: "memory");
        __builtin_amdgcn_s_barrier();
        cur ^= 1;
      }

      // ---- tail: square+pack, lane-local PV (no LDS, no barriers) ----
      #pragma unroll
      for (int ks = 0; ks < 2; ++ks) {
        bf16x8 aP[4];
        #pragma unroll
        for (int a = 0; a < 4; ++a)
          aP[a] = *reinterpret_cast<const bf16x8*>(
              Abp + (size_t)(a * 16 + l15) * CAP + i0 + wi * 64 + ks * 32 + l4 * 8);
        #pragma unroll
        for (int n = 0; n < 2; ++n) {
          const f32x4 s0 = acc[2 * ks][n];
          const f32x4 s1 = acc[2 * ks + 1][n];
          u32x4 tw;
          tw[0] = (uint32_t)bfbits(pwr(s0[0], expK)) |
                  ((uint32_t)bfbits(pwr(s0[1], expK)) << 16);
          tw[1] = (uint32_t)bfbits(pwr(s0[2], expK)) |
                  ((uint32_t)bfbits(pwr(s0[3], expK)) << 16);
          tw[2] = (uint32_t)bfbits(pwr(s1[0], expK)) |
                  ((uint32_t)bfbits(pwr(s1[1], expK)) << 16);
          tw[3] = (uint32_t)bfbits(pwr(s1[2], expK)) |
                  ((uint32_t)bfbits(pwr(s1[3], expK)) << 16);
          const bf16x8 bP = __builtin_bit_cast(bf16x8, tw);
          __builtin_amdgcn_s_setprio(1);
          #pragma unroll
          for (int a = 0; a < 4; ++a)
            accO[a][n] = __builtin_amdgcn_mfma_f32_16x16x32_bf16(
                aP[a], bP, accO[a][n], 0, 0, 0);
          __builtin_amdgcn_s_setprio(0);
        }
      }
    }
  }

  // ---- cross-wi reduce via LDS (unconditional: zeros for ntiles==0) ----
  __syncthreads();                 // everyone done with lA/lB
  float* rb = (float*)smem;        // 32KB: [wj 4][p 64][j 32] floats
  if (wi == 1) {
    #pragma unroll
    for (int a = 0; a < 4; ++a)
      #pragma unroll
      for (int n = 0; n < 2; ++n)
        #pragma unroll
        for (int r = 0; r < 4; ++r)
          rb[wj * 2048 + (a * 16 + l4 * 4 + r) * 32 + n * 16 + l15] =
              accO[a][n][r];
  }
  __syncthreads();
  if (wi == 0) {
    float* po = partial + (size_t)split * NPROPS * CAP;
    #pragma unroll
    for (int a = 0; a < 4; ++a)
      #pragma unroll
      for (int n = 0; n < 2; ++n)
        #pragma unroll
        for (int r = 0; r < 4; ++r) {
          const int p = a * 16 + l4 * 4 + r;
          const int jl = wj * 32 + n * 16 + l15;
          po[(size_t)p * CAP + j0 + jl] =
              accO[a][n][r] + rb[wj * 2048 + p * 32 + n * 16 + l15];
        }
  }
}

extern "C" void kernel_launch(void* const* d_in, const int* in_sizes, int n_in,
                              void* d_out, int out_size, void* d_ws, size_t ws_size,
                              hipStream_t stream) {
  (void)in_sizes; (void)n_in; (void)out_size;
  const float* Alpha = (const float*)d_in[0];
  const float* X_ref = (const float*)d_in[1];
  const float* desc  = (const float*)d_in[2];
  const int*   Z_ref = (const int*)d_in[3];
  const int*   Z     = (const int*)d_in[4];
  const int*   expK  = (const int*)d_in[5];
  float* out = (float*)d_out;

  char* ws = (char*)d_ws;
  size_t off = 0;
  auto alloc = [&](size_t b) { void* p = ws + off; off = (off + b + 255) & ~255ULL; return p; };

  int* perm_i = (int*)alloc(CAP * 4);
  int* perm_j = (int*)alloc(CAP * 4);
  int* ioff   = (int*)alloc(8 * 4);
  int* joff   = (int*)alloc(8 * 4);
  __hip_bfloat16* Xr_g = (__hip_bfloat16*)alloc((size_t)CAP * DFEAT * 2);
  __hip_bfloat16* Xi_g = (__hip_bfloat16*)alloc((size_t)CAP * DFEAT * 2);
  __hip_bfloat16* Ab_g = (__hip_bfloat16*)alloc((size_t)NPROPS * CAP * 2);

  // nsplit=8 -> grid 544 blocks of 512 thr = 2.125 blocks/CU (2 resident)
  int nsplit = 8;
  while (nsplit > 1 && off + (size_t)nsplit * NPROPS * CAP * 4 > ws_size) nsplit >>= 1;
  float* partial = (float*)alloc((size_t)nsplit * NPROPS * CAP * 4);

  partition2_kernel<<<dim3(2), 256, 0, stream>>>(
      Z_ref, Z, perm_i, perm_j, ioff, joff);

  gather_all<<<dim3(2 * XSEC + NPROPS * (CAP / 4) / 256), 256, 0, stream>>>(
      X_ref, desc, Alpha, perm_i, perm_j, Xr_g, Xi_g, Ab_g);

  const int grid = NSTRIP * nsplit;          // divisible by 8
  fused_poly_kernel<<<dim3(grid), 512, 0, stream>>>(
      Xr_g, Xi_g, Ab_g, ioff, joff, expK, partial, nsplit, grid / 8);

  reduce_scatter<<<dim3(NPROPS * (CAP / 4) / 256), 256, 0, stream>>>(
      partial, perm_j, out, nsplit);
}